// Round 1
// baseline (485.258 us; speedup 1.0000x reference)
//
#include <hip/hip_runtime.h>
#include <math.h>

// HybridSNN: time-collapsed spiking CNN.
// Stages:
//  kA: conv0(s2,p3,k7) + BN + ReLU + maxpool(3,s2,p1)       -> h    [256][16][1025] f32
//  kB: conv1(s2,p2,k5) + 16-step LIF (const input, analytic) -> m1  [256][32][513]  u16 bitmask over t
//  kC: maxpool on spikes = OR of neighbor masks              -> mp  [256][32][257]  u16
//  kD: conv2(s2,p1,k3) over bits (all 16 t) + LIF2 in-reg    -> s2  [256][64][129]  u16
//  kE: popcount-mean + fc1 + LIF3 + fc2 + mean over t        -> out [256][5]        f32

#define NB 256
#define LQ 2049
#define LP 1025
#define LJ1 513
#define LP1 257
#define LJ2 129

__global__ void kA_conv0(const float* __restrict__ x,
                         const float* __restrict__ w0,
                         const float* __restrict__ b0,
                         const float* __restrict__ bng,
                         const float* __restrict__ bnb,
                         const float* __restrict__ bnm,
                         const float* __restrict__ bnv,
                         float* __restrict__ h) {
  int tid = blockIdx.x * blockDim.x + threadIdx.x;
  const int total = NB * 16 * LP;
  if (tid >= total) return;
  int p = tid % LP;
  int rem = tid / LP;
  int c = rem % 16;
  int b = rem / 16;

  const float* xb = x + (size_t)b * 4097;
  float wv[7];
#pragma unroll
  for (int k = 0; k < 7; ++k) wv[k] = w0[c * 7 + k];
  // correctly-rounded fp32 rsqrt via double (matches lax.rsqrt to <=1ulp)
  float rs = (float)(1.0 / sqrt((double)bnv[c] + 1e-5));
  float g = bng[c], bb = bnb[c], m = bnm[c], bc = b0[c];

  float hm = -INFINITY;
#pragma unroll
  for (int dq = -1; dq <= 1; ++dq) {
    int q = 2 * p + dq;
    if (q < 0 || q >= LQ) continue;
    float s = 0.f;
    int base = 2 * q - 3;
#pragma unroll
    for (int k = 0; k < 7; ++k) {
      int idx = base + k;
      if (idx >= 0 && idx < 4097) s = fmaf(xb[idx], wv[k], s);
    }
    float y = s + bc;                 // conv + bias
    y = (y - m) * rs * g + bb;        // BN in reference order
    y = fmaxf(y, 0.f);                // ReLU
    hm = fmaxf(hm, y);                // maxpool
  }
  h[tid] = hm;
}

__global__ void kB_conv1_lif(const float* __restrict__ h,
                             const float* __restrict__ w1,
                             const float* __restrict__ b1,
                             unsigned short* __restrict__ mask1) {
  int tid = blockIdx.x * blockDim.x + threadIdx.x;
  const int total = NB * 32 * LJ1;
  if (tid >= total) return;
  int j = tid % LJ1;
  int rem = tid / LJ1;
  int c = rem % 32;
  int b = rem / 32;

  const float* hb = h + (size_t)b * 16 * LP;
  const float* wc = w1 + c * 16 * 5;
  float s = 0.f;
  int base = 2 * j - 2;
  for (int ic = 0; ic < 16; ++ic) {
    const float* hrow = hb + ic * LP;
    const float* wrow = wc + ic * 5;
#pragma unroll
    for (int k = 0; k < 5; ++k) {
      int idx = base + k;
      if (idx >= 0 && idx < LP) s = fmaf(hrow[idx], wrow[k], s);
    }
  }
  float xin = s + b1[c];

  // 16-step LIF with constant input (exact replication of the scan)
  float v = 0.f;
  unsigned msk = 0;
#pragma unroll
  for (int t = 0; t < 16; ++t) {
    v = v + (xin - v) * 0.5f;
    if (v >= 1.f) { msk |= (1u << t); v = 0.f; }
  }
  mask1[tid] = (unsigned short)msk;
}

__global__ void kC_mp(const unsigned short* __restrict__ mask1,
                      unsigned short* __restrict__ mpmask) {
  int tid = blockIdx.x * blockDim.x + threadIdx.x;
  const int total = NB * 32 * LP1;
  if (tid >= total) return;
  int p = tid % LP1;
  int rem = tid / LP1;
  int c = rem % 32;
  int b = rem / 32;

  const unsigned short* row = mask1 + (size_t)(b * 32 + c) * LJ1;
  int q0 = 2 * p - 1;
  unsigned m = 0;
  if (q0 >= 0) m |= row[q0];
  m |= row[q0 + 1];                   // 2p in [0,512], always valid
  if (q0 + 2 < LJ1) m |= row[q0 + 2];
  mpmask[tid] = (unsigned short)m;
}

__global__ void kD_conv2_lif(const unsigned short* __restrict__ mpmask,
                             const float* __restrict__ w2,
                             const float* __restrict__ b2,
                             unsigned short* __restrict__ s2mask) {
  int tid = blockIdx.x * blockDim.x + threadIdx.x;
  const int total = NB * 64 * LJ2;
  if (tid >= total) return;
  int j = tid % LJ2;
  int rem = tid / LJ2;
  int oc = rem % 64;
  int b = rem / 64;

  const unsigned short* mpb = mpmask + (size_t)b * 32 * LP1;
  float a[16];
#pragma unroll
  for (int t = 0; t < 16; ++t) a[t] = 0.f;

  int p0 = 2 * j - 1;
  for (int c = 0; c < 32; ++c) {
    const unsigned short* row = mpb + c * LP1;
    unsigned m0 = (p0 >= 0) ? (unsigned)row[p0] : 0u;
    unsigned m1 = (unsigned)row[p0 + 1];           // 2j in [0,256], valid
    unsigned m2 = (p0 + 2 < LP1) ? (unsigned)row[p0 + 2] : 0u;
    if ((m0 | m1 | m2) == 0u) continue;            // wave-uniform skip when possible
    const float* wc = w2 + (size_t)(oc * 32 + c) * 3;
    float wa = wc[0], wb = wc[1], wcv = wc[2];
#pragma unroll
    for (int t = 0; t < 16; ++t) {
      a[t] = fmaf(wa, (float)((m0 >> t) & 1u), a[t]);
      a[t] = fmaf(wb, (float)((m1 >> t) & 1u), a[t]);
      a[t] = fmaf(wcv, (float)((m2 >> t) & 1u), a[t]);
    }
  }

  float bc = b2[oc];
  float v = 0.f;
  unsigned msk = 0;
#pragma unroll
  for (int t = 0; t < 16; ++t) {
    float xin = a[t] + bc;
    v = v + (xin - v) * 0.5f;
    if (v >= 1.f) { msk |= (1u << t); v = 0.f; }
  }
  s2mask[tid] = (unsigned short)msk;
}

__global__ void kE_head(const unsigned short* __restrict__ s2mask,
                        const float* __restrict__ fc1w,
                        const float* __restrict__ fc1b,
                        const float* __restrict__ fc2w,
                        const float* __restrict__ fc2b,
                        float* __restrict__ out) {
  __shared__ float meanL[16][64];
  __shared__ unsigned s3m[32];
  int b = blockIdx.x;
  int oc = threadIdx.x;  // 64 threads

  const unsigned short* row = s2mask + ((size_t)b * 64 + oc) * LJ2;
  int cnt[16];
#pragma unroll
  for (int t = 0; t < 16; ++t) cnt[t] = 0;
  for (int jj = 0; jj < LJ2; ++jj) {
    unsigned m = row[jj];
#pragma unroll
    for (int t = 0; t < 16; ++t) cnt[t] += (int)((m >> t) & 1u);
  }
#pragma unroll
  for (int t = 0; t < 16; ++t) meanL[t][oc] = (float)cnt[t] / 129.f;
  __syncthreads();

  if (oc < 32) {
    int o = oc;
    const float* wrow = fc1w + o * 64;
    float bb = fc1b[o];
    float v = 0.f;
    unsigned msk = 0;
    for (int t = 0; t < 16; ++t) {
      float s = 0.f;
      for (int d = 0; d < 64; ++d) s = fmaf(meanL[t][d], wrow[d], s);
      float xin = s + bb;
      v = v + (xin - v) * 0.5f;
      if (v >= 1.f) { msk |= (1u << t); v = 0.f; }
    }
    s3m[o] = msk;
  }
  __syncthreads();

  if (oc < 5) {
    int q = oc;
    const float* wrow = fc2w + q * 32;
    float bb = fc2b[q];
    float acc = 0.f;
    for (int t = 0; t < 16; ++t) {
      float s = 0.f;
      for (int o = 0; o < 32; ++o) s += (((s3m[o] >> t) & 1u) ? wrow[o] : 0.f);
      acc += (s + bb);
    }
    out[b * 5 + q] = acc / 16.f;
  }
}

extern "C" void kernel_launch(void* const* d_in, const int* in_sizes, int n_in,
                              void* d_out, int out_size, void* d_ws, size_t ws_size,
                              hipStream_t stream) {
  const float* x   = (const float*)d_in[0];
  const float* w0  = (const float*)d_in[1];
  const float* b0  = (const float*)d_in[2];
  const float* bng = (const float*)d_in[3];
  const float* bnb = (const float*)d_in[4];
  const float* bnm = (const float*)d_in[5];
  const float* bnv = (const float*)d_in[6];
  const float* w1  = (const float*)d_in[7];
  const float* b1  = (const float*)d_in[8];
  const float* w2  = (const float*)d_in[9];
  const float* b2  = (const float*)d_in[10];
  const float* f1w = (const float*)d_in[11];
  const float* f1b = (const float*)d_in[12];
  const float* f2w = (const float*)d_in[13];
  const float* f2b = (const float*)d_in[14];
  float* out = (float*)d_out;

  char* ws = (char*)d_ws;
  size_t sz_h  = (size_t)NB * 16 * LP * 4;      // 16.8 MB
  size_t sz_m1 = (size_t)NB * 32 * LJ1 * 2;     //  8.4 MB
  size_t sz_mp = (size_t)NB * 32 * LP1 * 2;     //  4.2 MB
  size_t sz_s2 = (size_t)NB * 64 * LJ2 * 2;     //  4.2 MB
  size_t off_m1 = sz_h;
  size_t off_mp = off_m1 + sz_m1;
  size_t off_s2 = off_mp + sz_mp;
  if (ws_size < off_s2 + sz_s2) return;         // ~33.6 MB needed

  float* h = (float*)ws;
  unsigned short* m1 = (unsigned short*)(ws + off_m1);
  unsigned short* mp = (unsigned short*)(ws + off_mp);
  unsigned short* s2 = (unsigned short*)(ws + off_s2);

  {
    int total = NB * 16 * LP;
    kA_conv0<<<(total + 255) / 256, 256, 0, stream>>>(x, w0, b0, bng, bnb, bnm, bnv, h);
  }
  {
    int total = NB * 32 * LJ1;
    kB_conv1_lif<<<(total + 255) / 256, 256, 0, stream>>>(h, w1, b1, m1);
  }
  {
    int total = NB * 32 * LP1;
    kC_mp<<<(total + 255) / 256, 256, 0, stream>>>(m1, mp);
  }
  {
    int total = NB * 64 * LJ2;
    kD_conv2_lif<<<(total + 255) / 256, 256, 0, stream>>>(mp, w2, b2, s2);
  }
  kE_head<<<NB, 64, 0, stream>>>(s2, f1w, f1b, f2w, f2b, out);
}

// Round 2
// 243.434 us; speedup vs baseline: 1.9934x; 1.9934x over previous
//
#include <hip/hip_runtime.h>
#include <math.h>

// HybridSNN: time-collapsed spiking CNN (exact fp32 replication, bit-exact orders).
//  kP: precompute rs[c] (double rsqrt), transposed w1t/w2t into ws
//  kA: conv0+BN+ReLU+maxpool            -> h    [256][16][1025] f32   (LDS-staged x)
//  kB: conv1 + 16-step LIF (const inp)  -> m1   [256][32][520]  u16   (LDS tile GEMM)
//  kC: maxpool on spikes = OR masks     -> mp   [256][32][258]  u16
//  kD: conv2 over bits + LIF2           -> s2   [256][64][132]  u16   (LDS bitfloat GEMM)
//  kE: popcount-mean + fc1 + LIF3 + fc2 -> out  [256][5]        f32

#define NB 256
#define LX 4097
#define LQ 2049
#define LP 1025
#define LJ1 513
#define LP1 257
#define LJ2 129

#define M1S 520
#define MPS 258
#define S2S 132

typedef float f32x4 __attribute__((ext_vector_type(4)));

__global__ __launch_bounds__(256) void kP_setup(const float* __restrict__ w1,
                                                const float* __restrict__ w2,
                                                const float* __restrict__ bnv,
                                                float* __restrict__ w1t,
                                                float* __restrict__ w2t,
                                                float* __restrict__ rs) {
  int tid = threadIdx.x;
  if (tid < 16) rs[tid] = (float)(1.0 / sqrt((double)bnv[tid] + 1e-5));
  for (int idx = tid; idx < 32 * 16 * 5; idx += 256) {
    int k = idx % 5; int r = idx / 5; int ic = r % 16; int c = r / 16;
    w1t[(ic * 5 + k) * 32 + c] = w1[idx];
  }
  for (int idx = tid; idx < 64 * 32 * 3; idx += 256) {
    int k = idx % 3; int r = idx / 3; int c = r % 32; int oc = r / 32;
    w2t[(c * 3 + k) * 64 + oc] = w2[idx];
  }
}

__global__ __launch_bounds__(256) void kA_conv0(const float* __restrict__ x,
                                                const float* __restrict__ w0,
                                                const float* __restrict__ b0,
                                                const float* __restrict__ bng,
                                                const float* __restrict__ bnb,
                                                const float* __restrict__ bnm,
                                                const float* __restrict__ rs_,
                                                float* __restrict__ h) {
  __shared__ float xs[828];
  int bid = blockIdx.x;
  int b = bid / 5, pt = bid % 5;
  int P0 = pt * 205;
  int tid = threadIdx.x;
  const float* xb = x + (size_t)b * LX;
  int x0 = 4 * P0 - 5;
  for (int i = tid; i < 828; i += 256) {
    int gi = x0 + i;
    xs[i] = (gi >= 0 && gi < LX) ? xb[gi] : 0.f;
  }
  __syncthreads();
  if (tid >= 205) return;
  int p = P0 + tid;
  float win[12];
  {
    const f32x4* xv = (const f32x4*)xs;
    f32x4 a = xv[tid];
    f32x4 bq = xv[tid + 1];
    f32x4 cq = xv[tid + 2];
    win[0] = a.x; win[1] = a.y; win[2] = a.z; win[3] = a.w;
    win[4] = bq.x; win[5] = bq.y; win[6] = bq.z; win[7] = bq.w;
    win[8] = cq.x; win[9] = cq.y; win[10] = cq.z; win[11] = cq.w;
  }
  for (int c = 0; c < 16; ++c) {
    float wv[7];
#pragma unroll
    for (int k = 0; k < 7; ++k) wv[k] = w0[c * 7 + k];
    float rs = rs_[c], g = bng[c], bb = bnb[c], m = bnm[c], bc = b0[c];
    float hm = -INFINITY;
#pragma unroll
    for (int dq = -1; dq <= 1; ++dq) {
      int q = 2 * p + dq;
      if (q < 0 || q >= LQ) continue;
      float s = 0.f;
      int base = 2 * dq + 2;
#pragma unroll
      for (int k = 0; k < 7; ++k) s = fmaf(win[base + k], wv[k], s);
      float y = s + bc;
      y = (y - m) * rs * g + bb;
      y = fmaxf(y, 0.f);
      hm = fmaxf(hm, y);
    }
    h[((size_t)b * 16 + c) * LP + p] = hm;
  }
}

__global__ __launch_bounds__(256) void kB_conv1_lif(const float* __restrict__ h,
                                                    const float* __restrict__ w1t_g,
                                                    const float* __restrict__ b1,
                                                    unsigned short* __restrict__ m1) {
  __shared__ float hs[16 * 260];
  __shared__ float wl[16 * 5 * 32];
  int bid = blockIdx.x;
  int b = bid / 5, jt = bid % 5;
  int J0 = jt * 128;
  int tid = threadIdx.x;
  int c = tid & 31, jg = tid >> 5;

  {
    const float* hb = h + (size_t)b * 16 * LP;
    int p0 = 2 * J0 - 2;
    for (int i = tid; i < 16 * 260; i += 256) {
      int ic = i / 260, q = i - ic * 260;
      int p = p0 + q;
      hs[i] = (p >= 0 && p < LP) ? hb[ic * LP + p] : 0.f;
    }
    for (int i = tid; i < 2560; i += 256) wl[i] = w1t_g[i];
  }
  __syncthreads();
  int jbase = J0 + jg * 16;
  if (jbase > 512) return;

  float acc[16];
#pragma unroll
  for (int i = 0; i < 16; ++i) acc[i] = 0.f;

  for (int ic = 0; ic < 16; ++ic) {
    float win[36];
    const f32x4* row = (const f32x4*)(hs + ic * 260 + 32 * jg);
#pragma unroll
    for (int i = 0; i < 9; ++i) {
      f32x4 v = row[i];
      win[4 * i] = v.x; win[4 * i + 1] = v.y; win[4 * i + 2] = v.z; win[4 * i + 3] = v.w;
    }
    float wv[5];
#pragma unroll
    for (int k = 0; k < 5; ++k) wv[k] = wl[(ic * 5 + k) * 32 + c];
#pragma unroll
    for (int j = 0; j < 16; ++j) {
#pragma unroll
      for (int k = 0; k < 5; ++k) acc[j] = fmaf(win[2 * j + k], wv[k], acc[j]);
    }
  }

  float bc = b1[c];
  unsigned mskv[16];
#pragma unroll
  for (int j = 0; j < 16; ++j) {
    float xin = acc[j] + bc;
    float v = 0.f; unsigned mm = 0;
#pragma unroll
    for (int t = 0; t < 16; ++t) {
      v = v + (xin - v) * 0.5f;
      if (v >= 1.f) { mm |= (1u << t); v = 0.f; }
    }
    mskv[j] = mm;
  }
  size_t rowo = ((size_t)b * 32 + c) * M1S + jbase;
  if (jbase + 15 < LJ1) {
    uint4 u0, u1;
    u0.x = mskv[0] | (mskv[1] << 16);
    u0.y = mskv[2] | (mskv[3] << 16);
    u0.z = mskv[4] | (mskv[5] << 16);
    u0.w = mskv[6] | (mskv[7] << 16);
    u1.x = mskv[8] | (mskv[9] << 16);
    u1.y = mskv[10] | (mskv[11] << 16);
    u1.z = mskv[12] | (mskv[13] << 16);
    u1.w = mskv[14] | (mskv[15] << 16);
    *(uint4*)(m1 + rowo) = u0;
    *(uint4*)(m1 + rowo + 8) = u1;
  } else {
    for (int j = 0; j < 16; ++j)
      if (jbase + j < LJ1) m1[rowo + j] = (unsigned short)mskv[j];
  }
}

__global__ __launch_bounds__(256) void kC_mp(const unsigned short* __restrict__ m1,
                                             unsigned short* __restrict__ mp) {
  int tid = blockIdx.x * blockDim.x + threadIdx.x;
  const int total = NB * 32 * LP1;
  if (tid >= total) return;
  int p = tid % LP1;
  int rem = tid / LP1;
  int c = rem % 32;
  int b = rem / 32;
  const unsigned short* row = m1 + (size_t)(b * 32 + c) * M1S;
  int q0 = 2 * p - 1;
  unsigned m = 0;
  if (q0 >= 0) m |= row[q0];
  m |= row[q0 + 1];
  if (q0 + 2 < LJ1) m |= row[q0 + 2];
  mp[(size_t)(b * 32 + c) * MPS + p] = (unsigned short)m;
}

__global__ __launch_bounds__(256) void kD_conv2_lif(const unsigned short* __restrict__ mp,
                                                    const float* __restrict__ w2t_g,
                                                    const float* __restrict__ b2,
                                                    unsigned short* __restrict__ s2) {
  __shared__ float wl[32 * 3 * 64];   // 6144 f32
  __shared__ float F[16 * 33 * 20];   // 10560 f32 (bitfloats, t padded 16->20)
  int bid = blockIdx.x;
  int b = bid / 9, jt = bid % 9;
  int J0 = jt * 16;
  int tid = threadIdx.x;
  int jl = tid >> 4;          // 0..15
  int th = (tid >> 3) & 1;    // t-half
  int ocg = tid & 7;          // oc-group of 8

  for (int i = tid; i < 6144; i += 256) wl[i] = w2t_g[i];

  float acc[8][8];
#pragma unroll
  for (int o = 0; o < 8; ++o)
#pragma unroll
    for (int t = 0; t < 8; ++t) acc[o][t] = 0.f;

  for (int ch = 0; ch < 2; ++ch) {
    __syncthreads();
    // convert bits -> floats for this c-half
    for (int it = tid; it < 528; it += 256) {
      int cl = it / 33, ridx = it - cl * 33;
      int p = 2 * J0 - 1 + ridx;
      int c = ch * 16 + cl;
      unsigned m = (p >= 0 && p < LP1)
                       ? (unsigned)mp[((size_t)b * 32 + c) * MPS + p] : 0u;
      float* Fr = F + (cl * 33 + ridx) * 20;
#pragma unroll
      for (int t = 0; t < 16; ++t) Fr[t] = (float)((m >> t) & 1u);
    }
    __syncthreads();
    for (int cl = 0; cl < 16; ++cl) {
#pragma unroll
      for (int k = 0; k < 3; ++k) {
        int c = ch * 16 + cl;
        const f32x4* wp = (const f32x4*)(wl + ((c * 3 + k) * 64 + ocg * 8));
        f32x4 wa = wp[0], wb = wp[1];
        const f32x4* fp = (const f32x4*)(F + (cl * 33 + 2 * jl + k) * 20 + th * 8);
        f32x4 fa = fp[0], fb = fp[1];
        float wv[8] = {wa.x, wa.y, wa.z, wa.w, wb.x, wb.y, wb.z, wb.w};
        float bf[8] = {fa.x, fa.y, fa.z, fa.w, fb.x, fb.y, fb.z, fb.w};
#pragma unroll
        for (int o = 0; o < 8; ++o)
#pragma unroll
          for (int t = 0; t < 8; ++t)
            acc[o][t] = fmaf(wv[o], bf[t], acc[o][t]);
      }
    }
  }

  // exchange t-halves with partner lane (tid ^ 8), then LIF
  float* accf = &acc[0][0];
  float got[32];
#pragma unroll
  for (int i = 0; i < 32; ++i) {
    float send = th ? accf[i] : accf[32 + i];
    got[i] = __shfl_xor(send, 8);
  }
  int obase = th ? 4 : 0;
  int jg_ = J0 + jl;
  for (int o = 0; o < 4; ++o) {
    int oc = ocg * 8 + obase + o;
    float av[16];
#pragma unroll
    for (int t = 0; t < 8; ++t)
      av[t] = th ? got[o * 8 + t] : acc[o][t];
#pragma unroll
    for (int t = 8; t < 16; ++t)
      av[t] = th ? acc[4 + o][t - 8] : got[o * 8 + (t - 8)];
    float bc = b2[oc];
    float v = 0.f; unsigned mm = 0;
#pragma unroll
    for (int t = 0; t < 16; ++t) {
      float xin = av[t] + bc;
      v = v + (xin - v) * 0.5f;
      if (v >= 1.f) { mm |= (1u << t); v = 0.f; }
    }
    if (jg_ < LJ2) s2[((size_t)b * 64 + oc) * S2S + jg_] = (unsigned short)mm;
  }
}

__global__ __launch_bounds__(64) void kE_head(const unsigned short* __restrict__ s2,
                                              const float* __restrict__ fc1w,
                                              const float* __restrict__ fc1b,
                                              const float* __restrict__ fc2w,
                                              const float* __restrict__ fc2b,
                                              float* __restrict__ out) {
  __shared__ float meanL[16][64];
  __shared__ unsigned s3m[32];
  int b = blockIdx.x;
  int oc = threadIdx.x;

  const unsigned short* row = s2 + ((size_t)b * 64 + oc) * S2S;
  int cnt[16];
#pragma unroll
  for (int t = 0; t < 16; ++t) cnt[t] = 0;
  for (int jj = 0; jj < LJ2; ++jj) {
    unsigned m = row[jj];
#pragma unroll
    for (int t = 0; t < 16; ++t) cnt[t] += (int)((m >> t) & 1u);
  }
#pragma unroll
  for (int t = 0; t < 16; ++t) meanL[t][oc] = (float)cnt[t] / 129.f;
  __syncthreads();

  if (oc < 32) {
    int o = oc;
    const float* wrow = fc1w + o * 64;
    float bb = fc1b[o];
    float v = 0.f;
    unsigned msk = 0;
    for (int t = 0; t < 16; ++t) {
      float s = 0.f;
      for (int d = 0; d < 64; ++d) s = fmaf(meanL[t][d], wrow[d], s);
      float xin = s + bb;
      v = v + (xin - v) * 0.5f;
      if (v >= 1.f) { msk |= (1u << t); v = 0.f; }
    }
    s3m[o] = msk;
  }
  __syncthreads();

  if (oc < 5) {
    int q = oc;
    const float* wrow = fc2w + q * 32;
    float bb = fc2b[q];
    float accs = 0.f;
    for (int t = 0; t < 16; ++t) {
      float s = 0.f;
      for (int o = 0; o < 32; ++o) s += (((s3m[o] >> t) & 1u) ? wrow[o] : 0.f);
      accs += (s + bb);
    }
    out[b * 5 + q] = accs / 16.f;
  }
}

extern "C" void kernel_launch(void* const* d_in, const int* in_sizes, int n_in,
                              void* d_out, int out_size, void* d_ws, size_t ws_size,
                              hipStream_t stream) {
  const float* x   = (const float*)d_in[0];
  const float* w0  = (const float*)d_in[1];
  const float* b0  = (const float*)d_in[2];
  const float* bng = (const float*)d_in[3];
  const float* bnb = (const float*)d_in[4];
  const float* bnm = (const float*)d_in[5];
  const float* bnv = (const float*)d_in[6];
  const float* w1  = (const float*)d_in[7];
  const float* b1  = (const float*)d_in[8];
  const float* w2  = (const float*)d_in[9];
  const float* b2  = (const float*)d_in[10];
  const float* f1w = (const float*)d_in[11];
  const float* f1b = (const float*)d_in[12];
  const float* f2w = (const float*)d_in[13];
  const float* f2b = (const float*)d_in[14];
  float* out = (float*)d_out;

  char* ws = (char*)d_ws;
  size_t sz_h  = (size_t)NB * 16 * LP * 4;       // 16,793,600
  size_t sz_m1 = (size_t)NB * 32 * M1S * 2;      //  8,519,680 (s2 aliases here)
  size_t sz_mp = (size_t)NB * 32 * MPS * 2;      //  4,227,072
  size_t off_m1 = sz_h;
  size_t off_mp = off_m1 + sz_m1;
  size_t off_sm = off_mp + sz_mp;
  size_t sz_sm = (2560 + 6144 + 16) * 4;
  if (ws_size < off_sm + sz_sm) return;

  float* h = (float*)ws;
  unsigned short* m1 = (unsigned short*)(ws + off_m1);
  unsigned short* s2 = (unsigned short*)(ws + off_m1);  // alias: m1 dead after kC
  unsigned short* mp = (unsigned short*)(ws + off_mp);
  float* w1t = (float*)(ws + off_sm);
  float* w2t = w1t + 2560;
  float* rs  = w2t + 6144;

  kP_setup<<<1, 256, 0, stream>>>(w1, w2, bnv, w1t, w2t, rs);
  kA_conv0<<<NB * 5, 256, 0, stream>>>(x, w0, b0, bng, bnb, bnm, rs, h);
  kB_conv1_lif<<<NB * 5, 256, 0, stream>>>(h, w1t, b1, m1);
  {
    int total = NB * 32 * LP1;
    kC_mp<<<(total + 255) / 256, 256, 0, stream>>>(m1, mp);
  }
  kD_conv2_lif<<<NB * 9, 256, 0, stream>>>(mp, w2t, b2, s2);
  kE_head<<<NB, 64, 0, stream>>>(s2, f1w, f1b, f2w, f2b, out);
}

// Round 3
// 198.442 us; speedup vs baseline: 2.4453x; 1.2267x over previous
//
#include <hip/hip_runtime.h>
#include <math.h>

// HybridSNN: time-collapsed spiking CNN (exact fp32 replication, bit-exact orders).
//  kP: precompute rs[c] (double rsqrt), transposed w1t/w2t into ws
//  kA: conv0+BN+ReLU+maxpool            -> h    [256][16][1025] f32   (LDS-staged x)
//  kB: conv1 + 16-step LIF (const inp)  -> m1   [256][32][520]  u16   (LDS tile GEMM)
//  kD: maxpool(OR) + conv2 over bits + LIF2 -> s2 [256][64][132] u16  (LDS bitfloat GEMM,
//      spill-free: acc[4][16] per thread, no cross-lane exchange)
//  kE: popcount-mean + fc1 + LIF3 + fc2 -> out  [256][5]        f32

#define NB 256
#define LX 4097
#define LQ 2049
#define LP 1025
#define LJ1 513
#define LP1 257
#define LJ2 129

#define M1S 520
#define S2S 132

typedef float f32x4 __attribute__((ext_vector_type(4)));

__global__ __launch_bounds__(256) void kP_setup(const float* __restrict__ w1,
                                                const float* __restrict__ w2,
                                                const float* __restrict__ bnv,
                                                float* __restrict__ w1t,
                                                float* __restrict__ w2t,
                                                float* __restrict__ rs) {
  int tid = threadIdx.x;
  if (tid < 16) rs[tid] = (float)(1.0 / sqrt((double)bnv[tid] + 1e-5));
  for (int idx = tid; idx < 32 * 16 * 5; idx += 256) {
    int k = idx % 5; int r = idx / 5; int ic = r % 16; int c = r / 16;
    w1t[(ic * 5 + k) * 32 + c] = w1[idx];
  }
  for (int idx = tid; idx < 64 * 32 * 3; idx += 256) {
    int k = idx % 3; int r = idx / 3; int c = r % 32; int oc = r / 32;
    w2t[(c * 3 + k) * 64 + oc] = w2[idx];
  }
}

__global__ __launch_bounds__(256) void kA_conv0(const float* __restrict__ x,
                                                const float* __restrict__ w0,
                                                const float* __restrict__ b0,
                                                const float* __restrict__ bng,
                                                const float* __restrict__ bnb,
                                                const float* __restrict__ bnm,
                                                const float* __restrict__ rs_,
                                                float* __restrict__ h) {
  __shared__ float xs[828];
  int bid = blockIdx.x;
  int b = bid / 5, pt = bid % 5;
  int P0 = pt * 205;
  int tid = threadIdx.x;
  const float* xb = x + (size_t)b * LX;
  int x0 = 4 * P0 - 5;
  for (int i = tid; i < 828; i += 256) {
    int gi = x0 + i;
    xs[i] = (gi >= 0 && gi < LX) ? xb[gi] : 0.f;
  }
  __syncthreads();
  if (tid >= 205) return;
  int p = P0 + tid;
  float win[12];
  {
    const f32x4* xv = (const f32x4*)xs;
    f32x4 a = xv[tid];
    f32x4 bq = xv[tid + 1];
    f32x4 cq = xv[tid + 2];
    win[0] = a.x; win[1] = a.y; win[2] = a.z; win[3] = a.w;
    win[4] = bq.x; win[5] = bq.y; win[6] = bq.z; win[7] = bq.w;
    win[8] = cq.x; win[9] = cq.y; win[10] = cq.z; win[11] = cq.w;
  }
  for (int c = 0; c < 16; ++c) {
    float wv[7];
#pragma unroll
    for (int k = 0; k < 7; ++k) wv[k] = w0[c * 7 + k];
    float rs = rs_[c], g = bng[c], bb = bnb[c], m = bnm[c], bc = b0[c];
    float hm = -INFINITY;
#pragma unroll
    for (int dq = -1; dq <= 1; ++dq) {
      int q = 2 * p + dq;
      if (q < 0 || q >= LQ) continue;
      float s = 0.f;
      int base = 2 * dq + 2;
#pragma unroll
      for (int k = 0; k < 7; ++k) s = fmaf(win[base + k], wv[k], s);
      float y = s + bc;
      y = (y - m) * rs * g + bb;
      y = fmaxf(y, 0.f);
      hm = fmaxf(hm, y);
    }
    h[((size_t)b * 16 + c) * LP + p] = hm;
  }
}

__global__ __launch_bounds__(256) void kB_conv1_lif(const float* __restrict__ h,
                                                    const float* __restrict__ w1t_g,
                                                    const float* __restrict__ b1,
                                                    unsigned short* __restrict__ m1) {
  __shared__ float hs[16 * 260];
  __shared__ float wl[16 * 5 * 32];
  int bid = blockIdx.x;
  int b = bid / 5, jt = bid % 5;
  int J0 = jt * 128;
  int tid = threadIdx.x;
  int c = tid & 31, jg = tid >> 5;

  {
    const float* hb = h + (size_t)b * 16 * LP;
    int p0 = 2 * J0 - 2;
    for (int i = tid; i < 16 * 260; i += 256) {
      int ic = i / 260, q = i - ic * 260;
      int p = p0 + q;
      hs[i] = (p >= 0 && p < LP) ? hb[ic * LP + p] : 0.f;
    }
    for (int i = tid; i < 2560; i += 256) wl[i] = w1t_g[i];
  }
  __syncthreads();
  int jbase = J0 + jg * 16;
  if (jbase > 512) return;

  float acc[16];
#pragma unroll
  for (int i = 0; i < 16; ++i) acc[i] = 0.f;

  for (int ic = 0; ic < 16; ++ic) {
    float win[36];
    const f32x4* row = (const f32x4*)(hs + ic * 260 + 32 * jg);
#pragma unroll
    for (int i = 0; i < 9; ++i) {
      f32x4 v = row[i];
      win[4 * i] = v.x; win[4 * i + 1] = v.y; win[4 * i + 2] = v.z; win[4 * i + 3] = v.w;
    }
    float wv[5];
#pragma unroll
    for (int k = 0; k < 5; ++k) wv[k] = wl[(ic * 5 + k) * 32 + c];
#pragma unroll
    for (int j = 0; j < 16; ++j) {
#pragma unroll
      for (int k = 0; k < 5; ++k) acc[j] = fmaf(win[2 * j + k], wv[k], acc[j]);
    }
  }

  float bc = b1[c];
  unsigned mskv[16];
#pragma unroll
  for (int j = 0; j < 16; ++j) {
    float xin = acc[j] + bc;
    float v = 0.f; unsigned mm = 0;
#pragma unroll
    for (int t = 0; t < 16; ++t) {
      v = v + (xin - v) * 0.5f;
      if (v >= 1.f) { mm |= (1u << t); v = 0.f; }
    }
    mskv[j] = mm;
  }
  size_t rowo = ((size_t)b * 32 + c) * M1S + jbase;
  if (jbase + 15 < LJ1) {
    uint4 u0, u1;
    u0.x = mskv[0] | (mskv[1] << 16);
    u0.y = mskv[2] | (mskv[3] << 16);
    u0.z = mskv[4] | (mskv[5] << 16);
    u0.w = mskv[6] | (mskv[7] << 16);
    u1.x = mskv[8] | (mskv[9] << 16);
    u1.y = mskv[10] | (mskv[11] << 16);
    u1.z = mskv[12] | (mskv[13] << 16);
    u1.w = mskv[14] | (mskv[15] << 16);
    *(uint4*)(m1 + rowo) = u0;
    *(uint4*)(m1 + rowo + 8) = u1;
  } else {
    for (int j = 0; j < 16; ++j)
      if (jbase + j < LJ1) m1[rowo + j] = (unsigned short)mskv[j];
  }
}

// kD: maxpool(OR) folded in; conv2 over bitfloats; LIF2 local per thread.
// Block = (b, jt): 16 j x 64 oc. Thread = (jl, ocg): 1 j x 4 oc x 16 t.
__global__ __launch_bounds__(256) void kD_conv2_lif(const unsigned short* __restrict__ m1,
                                                    const float* __restrict__ w2t_g,
                                                    const float* __restrict__ b2,
                                                    unsigned short* __restrict__ s2) {
  __shared__ float wl[32 * 3 * 64];   // 24576 B
  __shared__ float F[8 * 33 * 20];    // 21120 B (bitfloats for 8-channel chunk, t padded to 20)
  int bid = blockIdx.x;
  int b = bid / 9, jt = bid % 9;
  int J0 = jt * 16;
  int tid = threadIdx.x;
  int ocg = tid & 15;   // oc group of 4
  int jl = tid >> 4;    // 0..15

  for (int i = tid; i < 6144; i += 256) wl[i] = w2t_g[i];

  float acc[4][16];
#pragma unroll
  for (int o = 0; o < 4; ++o)
#pragma unroll
    for (int t = 0; t < 16; ++t) acc[o][t] = 0.f;

  const unsigned short* m1b = m1 + (size_t)b * 32 * M1S;

  for (int ch = 0; ch < 4; ++ch) {
    __syncthreads();
    // build bitfloats for channels [ch*8, ch*8+8), positions p = 2*J0-1 .. 2*J0+31,
    // with maxpool OR folded in: mp[c][p] = OR(m1[c][2p-1..2p+1])
    for (int it = tid; it < 264; it += 256) {
      int cl = it / 33, ridx = it - cl * 33;
      int p = 2 * J0 - 1 + ridx;
      unsigned m = 0;
      if (p >= 0 && p < LP1) {
        const unsigned short* row = m1b + (size_t)(ch * 8 + cl) * M1S;
        int q0 = 2 * p - 1;
        if (q0 >= 0) m |= row[q0];
        m |= row[q0 + 1];
        if (q0 + 2 < LJ1) m |= row[q0 + 2];
      }
      float* Fr = F + it * 20;
#pragma unroll
      for (int t = 0; t < 16; ++t) Fr[t] = (float)((m >> t) & 1u);
    }
    __syncthreads();

    for (int cl = 0; cl < 8; ++cl) {
      int c = ch * 8 + cl;
#pragma unroll
      for (int k = 0; k < 3; ++k) {
        f32x4 wv = *(const f32x4*)(wl + (c * 3 + k) * 64 + ocg * 4);
        const f32x4* Fr = (const f32x4*)(F + (cl * 33 + 2 * jl + k) * 20);
        f32x4 f0 = Fr[0], f1 = Fr[1], f2 = Fr[2], f3 = Fr[3];
        float bf[16] = {f0.x, f0.y, f0.z, f0.w, f1.x, f1.y, f1.z, f1.w,
                        f2.x, f2.y, f2.z, f2.w, f3.x, f3.y, f3.z, f3.w};
#pragma unroll
        for (int o = 0; o < 4; ++o)
#pragma unroll
          for (int t = 0; t < 16; ++t)
            acc[o][t] = fmaf(wv[o], bf[t], acc[o][t]);
      }
    }
  }

  int j = J0 + jl;
  if (j < LJ2) {
#pragma unroll
    for (int o = 0; o < 4; ++o) {
      int oc = ocg * 4 + o;
      float bc = b2[oc];
      float v = 0.f; unsigned mm = 0;
#pragma unroll
      for (int t = 0; t < 16; ++t) {
        float xin = acc[o][t] + bc;
        v = v + (xin - v) * 0.5f;
        if (v >= 1.f) { mm |= (1u << t); v = 0.f; }
      }
      s2[((size_t)b * 64 + oc) * S2S + j] = (unsigned short)mm;
    }
  }
}

__global__ __launch_bounds__(64) void kE_head(const unsigned short* __restrict__ s2,
                                              const float* __restrict__ fc1w,
                                              const float* __restrict__ fc1b,
                                              const float* __restrict__ fc2w,
                                              const float* __restrict__ fc2b,
                                              float* __restrict__ out) {
  __shared__ float meanL[16][64];
  __shared__ unsigned s3m[32];
  int b = blockIdx.x;
  int oc = threadIdx.x;

  const unsigned short* row = s2 + ((size_t)b * 64 + oc) * S2S;
  int cnt[16];
#pragma unroll
  for (int t = 0; t < 16; ++t) cnt[t] = 0;
  for (int jj = 0; jj < LJ2; ++jj) {
    unsigned m = row[jj];
#pragma unroll
    for (int t = 0; t < 16; ++t) cnt[t] += (int)((m >> t) & 1u);
  }
#pragma unroll
  for (int t = 0; t < 16; ++t) meanL[t][oc] = (float)cnt[t] / 129.f;
  __syncthreads();

  if (oc < 32) {
    int o = oc;
    const float* wrow = fc1w + o * 64;
    float bb = fc1b[o];
    float v = 0.f;
    unsigned msk = 0;
    for (int t = 0; t < 16; ++t) {
      float s = 0.f;
      for (int d = 0; d < 64; ++d) s = fmaf(meanL[t][d], wrow[d], s);
      float xin = s + bb;
      v = v + (xin - v) * 0.5f;
      if (v >= 1.f) { msk |= (1u << t); v = 0.f; }
    }
    s3m[o] = msk;
  }
  __syncthreads();

  if (oc < 5) {
    int q = oc;
    const float* wrow = fc2w + q * 32;
    float bb = fc2b[q];
    float accs = 0.f;
    for (int t = 0; t < 16; ++t) {
      float s = 0.f;
      for (int o = 0; o < 32; ++o) s += (((s3m[o] >> t) & 1u) ? wrow[o] : 0.f);
      accs += (s + bb);
    }
    out[b * 5 + q] = accs / 16.f;
  }
}

extern "C" void kernel_launch(void* const* d_in, const int* in_sizes, int n_in,
                              void* d_out, int out_size, void* d_ws, size_t ws_size,
                              hipStream_t stream) {
  const float* x   = (const float*)d_in[0];
  const float* w0  = (const float*)d_in[1];
  const float* b0  = (const float*)d_in[2];
  const float* bng = (const float*)d_in[3];
  const float* bnb = (const float*)d_in[4];
  const float* bnm = (const float*)d_in[5];
  const float* bnv = (const float*)d_in[6];
  const float* w1  = (const float*)d_in[7];
  const float* b1  = (const float*)d_in[8];
  const float* w2  = (const float*)d_in[9];
  const float* b2  = (const float*)d_in[10];
  const float* f1w = (const float*)d_in[11];
  const float* f1b = (const float*)d_in[12];
  const float* f2w = (const float*)d_in[13];
  const float* f2b = (const float*)d_in[14];
  float* out = (float*)d_out;

  char* ws = (char*)d_ws;
  size_t sz_h  = (size_t)NB * 16 * LP * 4;       // 16,793,600
  size_t sz_m1 = (size_t)NB * 32 * M1S * 2;      //  8,519,680
  size_t sz_s2 = (size_t)NB * 64 * S2S * 2;      //  4,325,376
  size_t off_m1 = sz_h;
  size_t off_s2 = off_m1 + sz_m1;
  size_t off_sm = off_s2 + sz_s2;
  size_t sz_sm = (2560 + 6144 + 16) * 4;
  if (ws_size < off_sm + sz_sm) return;          // ~29.7 MB needed

  float* h = (float*)ws;
  unsigned short* m1 = (unsigned short*)(ws + off_m1);
  unsigned short* s2 = (unsigned short*)(ws + off_s2);
  float* w1t = (float*)(ws + off_sm);
  float* w2t = w1t + 2560;
  float* rs  = w2t + 6144;

  kP_setup<<<1, 256, 0, stream>>>(w1, w2, bnv, w1t, w2t, rs);
  kA_conv0<<<NB * 5, 256, 0, stream>>>(x, w0, b0, bng, bnb, bnm, rs, h);
  kB_conv1_lif<<<NB * 5, 256, 0, stream>>>(h, w1t, b1, m1);
  kD_conv2_lif<<<NB * 9, 256, 0, stream>>>(m1, w2t, b2, s2);
  kE_head<<<NB, 64, 0, stream>>>(s2, f1w, f1b, f2w, f2b, out);
}